// Round 8
// baseline (278.538 us; speedup 1.0000x reference)
//
#include <hip/hip_runtime.h>
#include <hip/hip_cooperative_groups.h>

namespace cg = cooperative_groups;

#define N_NODES  100000
#define N_EDGES  1200000
#define N_GRAPHS 1024

#define BUCK_SHIFT 10
#define BUCK_NODES 1024
#define NBUCK 98                     // ceil(100000/1024)
#define FBLK  256                    // cnt/fill blocks
#define CHUNK ((N_EDGES + FBLK - 1) / FBLK)   // 4688
#define ENC_BLOCKS 1563              // ceil(6250 waves / 4)

// bf16 pack/unpack (RNE)
__device__ __forceinline__ unsigned short f2bf(float f) {
  unsigned u = __float_as_uint(f);
  return (unsigned short)((u + 0x7fffu + ((u >> 16) & 1u)) >> 16);
}
__device__ __forceinline__ float bf2f(unsigned short b) {
  return __uint_as_float(((unsigned)b) << 16);
}

// ---- kernel A: edge blocks (0..255): bucket histogram + zero gsum;
//      node blocks: encoder + BN + h@W_gcn -> hw (bf16, UNscaled) ----
__global__ __launch_bounds__(256) void k_front(
    const int* __restrict__ ei, int* __restrict__ cnt, float* __restrict__ gsum,
    const float* __restrict__ x,
    const float* __restrict__ Wenc, const float* __restrict__ benc,
    const float* __restrict__ gamma, const float* __restrict__ beta,
    const float* __restrict__ mean,  const float* __restrict__ var,
    const float* __restrict__ Wgcn,
    unsigned short* __restrict__ hw) {
  int t = threadIdx.x;
  if (blockIdx.x < FBLK) {
    __shared__ int h[NBUCK];
    for (int i = t; i < NBUCK; i += 256) h[i] = 0;
    gsum[blockIdx.x * 256 + t] = 0.f;          // FBLK*256 == 65536 == N_GRAPHS*64
    __syncthreads();
    int start = blockIdx.x * CHUNK, end = min(start + CHUNK, N_EDGES);
    for (int e = start + t; e < end; e += 256)
      atomicAdd(&h[ei[N_EDGES + e] >> BUCK_SHIFT], 1);
    __syncthreads();
    for (int b = t; b < NBUCK; b += 256)
      cnt[b * FBLK + blockIdx.x] = h[b];
    return;
  }
  // ------- encoder role -------
  int lane = t & 63;
  int wv = ((blockIdx.x - FBLK) * 256 + t) >> 6;   // 16 nodes per wave
  if (wv >= 6250) return;
  float be = benc[lane];
  float sc = gamma[lane] * rsqrtf(var[lane] + 1e-5f);
  float mu = mean[lane], bt = beta[lane];
  float w0 = Wenc[lane], w1 = Wenc[64 + lane], w2 = Wenc[128 + lane], w3 = Wenc[192 + lane];
  float wreg[64];
  #pragma unroll
  for (int k = 0; k < 64; ++k) wreg[k] = Wgcn[k * 64 + lane];   // W column j=lane
  int n0 = wv * 16;
  for (int i = 0; i < 16; ++i) {
    int n = n0 + i;                                  // 6250*16 = 100000 exact
    float4 xv = ((const float4*)x)[n];
    float h = fmaf(xv.w, w3, fmaf(xv.z, w2, fmaf(xv.y, w1, fmaf(xv.x, w0, be))));
    h = fmaxf(h, 0.f);                               // ReLU (dropout = identity)
    float hbn = (h - mu) * sc + bt;                  // BatchNorm (running stats)
    int hb = __float_as_int(hbn);
    float a0 = 0.f, a1 = 0.f, a2 = 0.f, a3 = 0.f;
    #pragma unroll
    for (int k = 0; k < 64; k += 4) {
      a0 = fmaf(__int_as_float(__builtin_amdgcn_readlane(hb, k)),     wreg[k],     a0);
      a1 = fmaf(__int_as_float(__builtin_amdgcn_readlane(hb, k + 1)), wreg[k + 1], a1);
      a2 = fmaf(__int_as_float(__builtin_amdgcn_readlane(hb, k + 2)), wreg[k + 2], a2);
      a3 = fmaf(__int_as_float(__builtin_amdgcn_readlane(hb, k + 3)), wreg[k + 3], a3);
    }
    hw[(size_t)n * 64 + lane] = f2bf((a0 + a1) + (a2 + a3));
  }
}

// ---- kernel B (cooperative, 256 blocks): colscan -> base -> fill ----
__global__ __launch_bounds__(256) void k_build(int* __restrict__ cnt,
                                               int* __restrict__ tot,
                                               int* __restrict__ base,
                                               const int* __restrict__ ei,
                                               int* __restrict__ binned) {
  cg::grid_group grid = cg::this_grid();
  int t = threadIdx.x, blk = blockIdx.x;
  int lane = t & 63, w = t >> 6;
  // phase 1: per-bucket exclusive scan over the 256 block counts (first 98 blocks)
  if (blk < NBUCK) {
    __shared__ int wsum[4];
    int v = cnt[blk * FBLK + t];
    int incl = v;
    #pragma unroll
    for (int off = 1; off < 64; off <<= 1) {
      int y = __shfl_up(incl, off);
      if (lane >= off) incl += y;
    }
    if (lane == 63) wsum[w] = incl;
    __syncthreads();
    if (t == 0) {
      int s = 0;
      #pragma unroll
      for (int i = 0; i < 4; ++i) { int x2 = wsum[i]; wsum[i] = s; s += x2; }
      tot[blk] = s;
    }
    __syncthreads();
    cnt[blk * FBLK + t] = wsum[w] + incl - v;
  }
  grid.sync();
  // phase 2: exclusive scan of 98 bucket totals (block 0)
  if (blk == 0) {
    __shared__ int s[256];
    int v = (t < NBUCK) ? tot[t] : 0;
    s[t] = v;
    __syncthreads();
    for (int off = 1; off < 256; off <<= 1) {
      int x2 = (t >= off) ? s[t - off] : 0;
      __syncthreads();
      s[t] += x2;
      __syncthreads();
    }
    if (t < NBUCK) base[t] = s[t] - v;
    if (t == 0) base[NBUCK] = N_EDGES;
  }
  grid.sync();
  // phase 3: deterministic fill (LDS cursors, zero global atomics)
  __shared__ int cur[NBUCK];
  for (int b = t; b < NBUCK; b += 256) cur[b] = base[b] + cnt[b * FBLK + blk];
  __syncthreads();
  int start = blk * CHUNK, end = min(start + CHUNK, N_EDGES);
  for (int e = start + t; e < end; e += 256) {
    int src = ei[e];
    int dst = ei[N_EDGES + e];
    int b = dst >> BUCK_SHIFT;
    int p = atomicAdd(&cur[b], 1);                 // LDS atomic
    binned[p] = src | ((dst & (BUCK_NODES - 1)) << 17);
  }
}

// ---- per-bucket: LDS hist+scan -> row_start/dis (coalesced), sort csr ----
__global__ __launch_bounds__(512) void k_csr(const int* __restrict__ base,
                                             const int* __restrict__ binned,
                                             int* __restrict__ csr,
                                             int* __restrict__ row_start,
                                             float* __restrict__ dis) {
  __shared__ int hist[BUCK_NODES];
  __shared__ int rs[BUCK_NODES];
  __shared__ int wsum[8];
  int t = threadIdx.x;
  int blk = blockIdx.x;
  int b0 = base[blk];
  int nE = base[blk + 1] - b0;
  int node0 = blk << BUCK_SHIFT;
  int nNodes = min(BUCK_NODES, N_NODES - node0);
  hist[t] = 0; hist[t + 512] = 0;
  __syncthreads();
  for (int i = t; i < nE; i += 512)
    atomicAdd(&hist[(unsigned)binned[b0 + i] >> 17], 1);
  __syncthreads();
  int x0 = hist[2 * t], x1 = hist[2 * t + 1];
  int a = x0 + x1;
  int lane = t & 63, w = t >> 6;
  int incl = a;
  #pragma unroll
  for (int off = 1; off < 64; off <<= 1) {
    int y = __shfl_up(incl, off);
    if (lane >= off) incl += y;
  }
  if (lane == 63) wsum[w] = incl;
  __syncthreads();
  if (w == 0) {
    int v = (lane < 8) ? wsum[lane] : 0;
    for (int off = 1; off < 8; off <<= 1) {
      int y = __shfl_up(v, off);
      if (lane >= off) v += y;
    }
    if (lane < 8) wsum[lane] = v;
  }
  __syncthreads();
  int woff = (w > 0) ? wsum[w - 1] : 0;
  int exclPair = woff + incl - a;
  rs[2 * t] = exclPair;
  rs[2 * t + 1] = exclPair + x0;
  __syncthreads();
  for (int n = t; n < BUCK_NODES; n += 512) {
    int cnt_n = ((n < BUCK_NODES - 1) ? rs[n + 1] : nE) - rs[n];
    hist[n] = rs[n];                           // reuse hist as scatter cursor
    if (n < nNodes) {
      row_start[node0 + n] = b0 + rs[n];
      dis[node0 + n] = rsqrtf((float)(cnt_n + 1));   // +1 self-loop
    }
  }
  if (t == 0 && blk == NBUCK - 1) row_start[N_NODES] = N_EDGES;
  __syncthreads();
  for (int i = t; i < nE; i += 512) {
    int v = binned[b0 + i];
    int d = (unsigned)v >> 17;
    int p = atomicAdd(&hist[d], 1);
    csr[b0 + p] = v & 0x1FFFF;                 // scatter confined to ~49KB region
  }
}

// ---- CSR gather (bf16 rows, per-edge dis fma): 4 nodes/wave, 4-acc ILP ----
__global__ __launch_bounds__(256) void k_gather(
    const int* __restrict__ row_start, const int* __restrict__ csr,
    const float* __restrict__ dis, const unsigned short* __restrict__ hw,
    const int* __restrict__ batch, const float* __restrict__ bgcn,
    float* __restrict__ gsum) {
  int lane = threadIdx.x & 63;
  int wv = blockIdx.x * 4 + (threadIdx.x >> 6);
  int nb = wv * 4;                       // 100000 = 4*25000, no tail
  if (nb >= N_NODES) return;
  float bias = bgcn[lane];
  float vout[4];
  int gid[4];
  #pragma unroll
  for (int k = 0; k < 4; ++k) {
    int n = nb + k;
    int st = row_start[n], en = row_start[n + 1];
    float dn = dis[n];
    float a0 = 0.f, a1 = 0.f, a2 = 0.f, a3 = 0.f;
    for (int c = st; c < en; c += 64) {
      int idx = c + lane;
      int sj = 0; float dj = 0.f;
      if (idx < en) { sj = csr[idx]; dj = dis[sj]; }
      int m = min(64, en - c);
      int j = 0;
      for (; j + 4 <= m; j += 4) {
        int s0 = __shfl(sj, j), s1 = __shfl(sj, j + 1);
        int s2 = __shfl(sj, j + 2), s3 = __shfl(sj, j + 3);
        float d0 = __shfl(dj, j), d1 = __shfl(dj, j + 1);
        float d2 = __shfl(dj, j + 2), d3 = __shfl(dj, j + 3);
        a0 = fmaf(d0, bf2f(hw[(size_t)s0 * 64 + lane]), a0);
        a1 = fmaf(d1, bf2f(hw[(size_t)s1 * 64 + lane]), a1);
        a2 = fmaf(d2, bf2f(hw[(size_t)s2 * 64 + lane]), a2);
        a3 = fmaf(d3, bf2f(hw[(size_t)s3 * 64 + lane]), a3);
      }
      for (; j < m; ++j) {
        int s = __shfl(sj, j);
        float d = __shfl(dj, j);
        a0 = fmaf(d, bf2f(hw[(size_t)s * 64 + lane]), a0);
      }
    }
    float self = bf2f(hw[(size_t)n * 64 + lane]);
    vout[k] = fmaxf(dn * (((a0 + a1) + (a2 + a3)) + dn * self) + bias, 0.f);
    gid[k] = batch[n];
  }
  float vs = vout[0];
  int cg_ = gid[0];
  #pragma unroll
  for (int k = 1; k < 4; ++k) {
    if (gid[k] == cg_) vs += vout[k];
    else {
      atomicAdd(&gsum[cg_ * 64 + lane], vs);
      vs = vout[k]; cg_ = gid[k];
    }
  }
  atomicAdd(&gsum[cg_ * 64 + lane], vs);
}

// ---- classifier; graph count via binary search on sorted batch ----
__global__ void k_cls(const float* __restrict__ gsum, const int* __restrict__ batch,
                      const float* __restrict__ W1, const float* __restrict__ b1,
                      const float* __restrict__ W2, const float* __restrict__ b2,
                      float* __restrict__ out) {
  __shared__ float gm[64];
  __shared__ int cntS;
  int j = threadIdx.x;
  int g = blockIdx.x;
  if (j == 0) {
    int lo = 0, hi = N_NODES;
    while (lo < hi) { int mid = (lo + hi) >> 1; if (batch[mid] < g) lo = mid + 1; else hi = mid; }
    int lo2 = lo, hi2 = N_NODES;
    while (lo2 < hi2) { int mid = (lo2 + hi2) >> 1; if (batch[mid] < g + 1) lo2 = mid + 1; else hi2 = mid; }
    cntS = lo2 - lo;
  }
  __syncthreads();
  float denom = fmaxf((float)cntS, 1.0f);
  gm[j] = gsum[g * 64 + j] / denom;
  __syncthreads();
  float hid = b1[j];
  #pragma unroll
  for (int k = 0; k < 64; ++k) hid += gm[k] * W1[k * 64 + j];
  hid = fmaxf(hid, 0.f);
  float o0 = hid * W2[j * 2 + 0];
  float o1 = hid * W2[j * 2 + 1];
  #pragma unroll
  for (int off = 32; off > 0; off >>= 1) {
    o0 += __shfl_down(o0, off);
    o1 += __shfl_down(o1, off);
  }
  if (j == 0) {
    out[g * 2 + 0] = o0 + b2[0];
    out[g * 2 + 1] = o1 + b2[1];
  }
}

extern "C" void kernel_launch(void* const* d_in, const int* in_sizes, int n_in,
                              void* d_out, int out_size, void* d_ws, size_t ws_size,
                              hipStream_t stream) {
  const float* x     = (const float*)d_in[0];
  const int*   ei    = (const int*)d_in[1];
  const int*   batch = (const int*)d_in[2];
  const float* Wenc  = (const float*)d_in[3];
  const float* benc  = (const float*)d_in[4];
  const float* gamma = (const float*)d_in[5];
  const float* beta  = (const float*)d_in[6];
  const float* mean  = (const float*)d_in[7];
  const float* var   = (const float*)d_in[8];
  const float* Wgcn  = (const float*)d_in[9];
  const float* bgcn  = (const float*)d_in[10];
  const float* W1    = (const float*)d_in[11];
  const float* b1    = (const float*)d_in[12];
  const float* W2    = (const float*)d_in[13];
  const float* b2    = (const float*)d_in[14];
  float* out = (float*)d_out;

  char* ws = (char*)d_ws;
  float*          gsum      = (float*)ws;          ws += (size_t)N_GRAPHS * 64 * 4;
  int*            cnt       = (int*)ws;            ws += (size_t)NBUCK * FBLK * 4;
  int*            tot       = (int*)ws;            ws += 128 * 4;
  int*            basep     = (int*)ws;            ws += 128 * 4;
  int*            binned    = (int*)ws;            ws += (size_t)N_EDGES * 4;
  int*            csr       = (int*)ws;            ws += (size_t)N_EDGES * 4;
  int*            row_start = (int*)ws;            ws += (size_t)(N_NODES + 32) * 4;
  float*          dis       = (float*)ws;          ws += (size_t)N_NODES * 4;
  unsigned short* hw        = (unsigned short*)ws; ws += (size_t)N_NODES * 64 * 2;

  k_front<<<FBLK + ENC_BLOCKS, 256, 0, stream>>>(ei, cnt, gsum, x, Wenc, benc, gamma,
                                                 beta, mean, var, Wgcn, hw);
  {
    void* args[] = {(void*)&cnt, (void*)&tot, (void*)&basep, (void*)&ei, (void*)&binned};
    hipLaunchCooperativeKernel((void*)k_build, dim3(FBLK), dim3(256), args, 0, stream);
  }
  k_csr<<<NBUCK, 512, 0, stream>>>(basep, binned, csr, row_start, dis);
  k_gather<<<(N_NODES / 16), 256, 0, stream>>>(row_start, csr, dis, hw, batch, bgcn, gsum);
  k_cls<<<N_GRAPHS, 64, 0, stream>>>(gsum, batch, W1, b1, W2, b2, out);
}

// Round 9
// 200.498 us; speedup vs baseline: 1.3892x; 1.3892x over previous
//
#include <hip/hip_runtime.h>

#define N_NODES  100000
#define N_EDGES  1200000
#define N_GRAPHS 1024

#define BUCK_SHIFT 10
#define BUCK_NODES 1024
#define NBUCK 98                     // ceil(100000/1024)
#define FBLK  512                    // cnt/fill blocks
#define CHUNK ((N_EDGES + FBLK - 1) / FBLK)   // 2344

// bf16 pack/unpack (RNE)
__device__ __forceinline__ unsigned short f2bf(float f) {
  unsigned u = __float_as_uint(f);
  return (unsigned short)((u + 0x7fffu + ((u >> 16) & 1u)) >> 16);
}
__device__ __forceinline__ float bf2f(unsigned short b) {
  return __uint_as_float(((unsigned)b) << 16);
}

// ---- pass 1: per-block bucket histogram -> cnt[b*FBLK+blk]; also zero gsum ----
__global__ __launch_bounds__(256) void k_cnt(const int* __restrict__ ei,
                                             int* __restrict__ cnt,
                                             float* __restrict__ gsum) {
  __shared__ int h[NBUCK];
  int t = threadIdx.x;
  for (int i = t; i < NBUCK; i += 256) h[i] = 0;
  int gi = blockIdx.x * 256 + t;
  if (gi < N_GRAPHS * 64) gsum[gi] = 0.f;
  __syncthreads();
  int start = blockIdx.x * CHUNK, end = min(start + CHUNK, N_EDGES);
  for (int e = start + t; e < end; e += 256)
    atomicAdd(&h[ei[N_EDGES + e] >> BUCK_SHIFT], 1);
  __syncthreads();
  for (int b = t; b < NBUCK; b += 256)
    cnt[b * FBLK + blockIdx.x] = h[b];
}

// ---- per-bucket exclusive scan over the 512 block counts (in place); totals ----
__global__ __launch_bounds__(256) void k_colscan(int* __restrict__ cnt,
                                                 int* __restrict__ tot) {
  __shared__ int wsum[4];
  int b = blockIdx.x, t = threadIdx.x;
  int v0 = cnt[b * FBLK + 2 * t], v1 = cnt[b * FBLK + 2 * t + 1];
  int a = v0 + v1;
  int lane = t & 63, w = t >> 6;
  int incl = a;
  #pragma unroll
  for (int off = 1; off < 64; off <<= 1) {
    int y = __shfl_up(incl, off);
    if (lane >= off) incl += y;
  }
  if (lane == 63) wsum[w] = incl;
  __syncthreads();
  if (t == 0) {
    int s = 0;
    #pragma unroll
    for (int i = 0; i < 4; ++i) { int x = wsum[i]; wsum[i] = s; s += x; }
    tot[b] = s;
  }
  __syncthreads();
  int excl = wsum[w] + incl - a;
  cnt[b * FBLK + 2 * t] = excl;
  cnt[b * FBLK + 2 * t + 1] = excl + v0;
}

// ---- exclusive scan of 98 bucket totals -> base; base[NBUCK]=N_EDGES ----
__global__ void k_base(const int* __restrict__ tot, int* __restrict__ base) {
  __shared__ int s[128];
  int t = threadIdx.x;
  int v = (t < NBUCK) ? tot[t] : 0;
  s[t] = v;
  __syncthreads();
  for (int off = 1; off < 128; off <<= 1) {
    int x = (t >= off) ? s[t - off] : 0;
    __syncthreads();
    s[t] += x;
    __syncthreads();
  }
  if (t < NBUCK) base[t] = s[t] - v;
  if (t == 0) base[NBUCK] = N_EDGES;
}

// ---- pass 2: deterministic fill (LDS cursors, zero global atomics) ----
__global__ __launch_bounds__(256) void k_fill(const int* __restrict__ ei,
                                              const int* __restrict__ cnt,
                                              const int* __restrict__ base,
                                              int* __restrict__ binned) {
  __shared__ int cur[NBUCK];
  int t = threadIdx.x, blk = blockIdx.x;
  for (int b = t; b < NBUCK; b += 256) cur[b] = base[b] + cnt[b * FBLK + blk];
  __syncthreads();
  int start = blk * CHUNK, end = min(start + CHUNK, N_EDGES);
  for (int e = start + t; e < end; e += 256) {
    int src = ei[e];
    int dst = ei[N_EDGES + e];
    int b = dst >> BUCK_SHIFT;
    int p = atomicAdd(&cur[b], 1);                 // LDS atomic
    binned[p] = src | ((dst & (BUCK_NODES - 1)) << 17);
  }
}

// ---- per-bucket (1024 thr): LDS hist+scan -> row_start/dis, sort csr ----
__global__ __launch_bounds__(1024) void k_csr(const int* __restrict__ base,
                                              const int* __restrict__ binned,
                                              int* __restrict__ csr,
                                              int* __restrict__ row_start,
                                              float* __restrict__ dis) {
  __shared__ int hist[BUCK_NODES];
  __shared__ int wsum[16];
  int t = threadIdx.x;
  int blk = blockIdx.x;
  int b0 = base[blk];
  int nE = base[blk + 1] - b0;
  int node0 = blk << BUCK_SHIFT;
  int nNodes = min(BUCK_NODES, N_NODES - node0);
  hist[t] = 0;
  __syncthreads();
  for (int i = t; i < nE; i += 1024)
    atomicAdd(&hist[(unsigned)binned[b0 + i] >> 17], 1);
  __syncthreads();
  int v = hist[t];                         // degree of node t in this bucket
  int lane = t & 63, w = t >> 6;
  int incl = v;
  #pragma unroll
  for (int off = 1; off < 64; off <<= 1) {
    int y = __shfl_up(incl, off);
    if (lane >= off) incl += y;
  }
  if (lane == 63) wsum[w] = incl;
  __syncthreads();
  if (t == 0) {
    int s = 0;
    #pragma unroll
    for (int i = 0; i < 16; ++i) { int x = wsum[i]; wsum[i] = s; s += x; }
  }
  __syncthreads();
  int excl = wsum[w] + incl - v;
  hist[t] = excl;                          // reuse hist as scatter cursor
  if (t < nNodes) {
    row_start[node0 + t] = b0 + excl;
    dis[node0 + t] = rsqrtf((float)(v + 1));     // +1 self-loop
  }
  if (t == 0 && blk == NBUCK - 1) row_start[N_NODES] = N_EDGES;
  __syncthreads();
  for (int i = t; i < nE; i += 1024) {
    int vv = binned[b0 + i];
    int d = (unsigned)vv >> 17;
    int p = atomicAdd(&hist[d], 1);
    csr[b0 + p] = vv & 0x1FFFF;            // scatter confined to ~49KB region
  }
}

// ---- encoder + BN + h@W_gcn (register W column + readlane broadcast, no LDS),
//      pre-scaled by dis[node], stored bf16 -> hws ----
__global__ __launch_bounds__(256) void k_enc(
    const float* __restrict__ x,
    const float* __restrict__ Wenc, const float* __restrict__ benc,
    const float* __restrict__ gamma, const float* __restrict__ beta,
    const float* __restrict__ mean,  const float* __restrict__ var,
    const float* __restrict__ Wgcn,  const float* __restrict__ dis,
    unsigned short* __restrict__ hws) {
  int lane = threadIdx.x & 63;
  int wv = (blockIdx.x * 256 + threadIdx.x) >> 6;   // 0..6249, 16 nodes each
  float be = benc[lane];
  float sc = gamma[lane] * rsqrtf(var[lane] + 1e-5f);
  float mu = mean[lane], bt = beta[lane];
  float w0 = Wenc[lane], w1 = Wenc[64 + lane], w2 = Wenc[128 + lane], w3 = Wenc[192 + lane];
  float wreg[64];
  #pragma unroll
  for (int k = 0; k < 64; ++k) wreg[k] = Wgcn[k * 64 + lane];   // W column j=lane
  int n0 = wv * 16;
  for (int i = 0; i < 16; ++i) {
    int n = n0 + i;                                  // 6250*16 = 100000 exact
    float4 xv = ((const float4*)x)[n];               // wave-uniform broadcast
    float h = fmaf(xv.w, w3, fmaf(xv.z, w2, fmaf(xv.y, w1, fmaf(xv.x, w0, be))));
    h = fmaxf(h, 0.f);                               // ReLU (dropout = identity)
    float hbn = (h - mu) * sc + bt;                  // BatchNorm (running stats)
    int hb = __float_as_int(hbn);
    float a0 = 0.f, a1 = 0.f, a2 = 0.f, a3 = 0.f;
    #pragma unroll
    for (int k = 0; k < 64; k += 4) {
      a0 = fmaf(__int_as_float(__builtin_amdgcn_readlane(hb, k)),     wreg[k],     a0);
      a1 = fmaf(__int_as_float(__builtin_amdgcn_readlane(hb, k + 1)), wreg[k + 1], a1);
      a2 = fmaf(__int_as_float(__builtin_amdgcn_readlane(hb, k + 2)), wreg[k + 2], a2);
      a3 = fmaf(__int_as_float(__builtin_amdgcn_readlane(hb, k + 3)), wreg[k + 3], a3);
    }
    float acc = ((a0 + a1) + (a2 + a3)) * dis[n];
    hws[(size_t)n * 64 + lane] = f2bf(acc);
  }
}

// ---- CSR gather (bf16 rows): 4 nodes/wave, 8-deep load unroll ----
__global__ __launch_bounds__(256) void k_gather(
    const int* __restrict__ row_start, const int* __restrict__ csr,
    const float* __restrict__ dis, const unsigned short* __restrict__ hws,
    const int* __restrict__ batch, const float* __restrict__ bgcn,
    float* __restrict__ gsum) {
  int lane = threadIdx.x & 63;
  int wv = blockIdx.x * 4 + (threadIdx.x >> 6);
  int nb = wv * 4;                       // 100000 = 4*25000, no tail
  if (nb >= N_NODES) return;
  float bias = bgcn[lane];
  float vout[4];
  int gid[4];
  #pragma unroll
  for (int k = 0; k < 4; ++k) {
    int n = nb + k;
    int st = row_start[n], en = row_start[n + 1];
    float dn = dis[n];
    float a0 = 0.f, a1 = 0.f, a2 = 0.f, a3 = 0.f;
    for (int c = st; c < en; c += 64) {
      int idx = c + lane;
      int sj = (idx < en) ? csr[idx] : 0;
      int m = min(64, en - c);
      int j = 0;
      for (; j + 8 <= m; j += 8) {
        int s0 = __shfl(sj, j),     s1 = __shfl(sj, j + 1);
        int s2 = __shfl(sj, j + 2), s3 = __shfl(sj, j + 3);
        int s4 = __shfl(sj, j + 4), s5 = __shfl(sj, j + 5);
        int s6 = __shfl(sj, j + 6), s7 = __shfl(sj, j + 7);
        float r0 = bf2f(hws[(size_t)s0 * 64 + lane]);
        float r1 = bf2f(hws[(size_t)s1 * 64 + lane]);
        float r2 = bf2f(hws[(size_t)s2 * 64 + lane]);
        float r3 = bf2f(hws[(size_t)s3 * 64 + lane]);
        float r4 = bf2f(hws[(size_t)s4 * 64 + lane]);
        float r5 = bf2f(hws[(size_t)s5 * 64 + lane]);
        float r6 = bf2f(hws[(size_t)s6 * 64 + lane]);
        float r7 = bf2f(hws[(size_t)s7 * 64 + lane]);
        a0 += r0; a1 += r1; a2 += r2; a3 += r3;
        a0 += r4; a1 += r5; a2 += r6; a3 += r7;
      }
      for (; j < m; ++j) {
        int s = __shfl(sj, j);
        a0 += bf2f(hws[(size_t)s * 64 + lane]);
      }
    }
    float self = bf2f(hws[(size_t)n * 64 + lane]);
    vout[k] = fmaxf(dn * (((a0 + a1) + (a2 + a3)) + self) + bias, 0.f);
    gid[k] = batch[n];
  }
  float vs = vout[0];
  int cg = gid[0];
  #pragma unroll
  for (int k = 1; k < 4; ++k) {
    if (gid[k] == cg) vs += vout[k];
    else {
      atomicAdd(&gsum[cg * 64 + lane], vs);
      vs = vout[k]; cg = gid[k];
    }
  }
  atomicAdd(&gsum[cg * 64 + lane], vs);
}

// ---- classifier; graph count via binary search on sorted batch ----
__global__ void k_cls(const float* __restrict__ gsum, const int* __restrict__ batch,
                      const float* __restrict__ W1, const float* __restrict__ b1,
                      const float* __restrict__ W2, const float* __restrict__ b2,
                      float* __restrict__ out) {
  __shared__ float gm[64];
  __shared__ int cntS;
  int j = threadIdx.x;
  int g = blockIdx.x;
  if (j == 0) {
    int lo = 0, hi = N_NODES;
    while (lo < hi) { int mid = (lo + hi) >> 1; if (batch[mid] < g) lo = mid + 1; else hi = mid; }
    int lo2 = lo, hi2 = N_NODES;
    while (lo2 < hi2) { int mid = (lo2 + hi2) >> 1; if (batch[mid] < g + 1) lo2 = mid + 1; else hi2 = mid; }
    cntS = lo2 - lo;
  }
  __syncthreads();
  float denom = fmaxf((float)cntS, 1.0f);
  gm[j] = gsum[g * 64 + j] / denom;
  __syncthreads();
  float hid = b1[j];
  #pragma unroll
  for (int k = 0; k < 64; ++k) hid += gm[k] * W1[k * 64 + j];
  hid = fmaxf(hid, 0.f);
  float o0 = hid * W2[j * 2 + 0];
  float o1 = hid * W2[j * 2 + 1];
  #pragma unroll
  for (int off = 32; off > 0; off >>= 1) {
    o0 += __shfl_down(o0, off);
    o1 += __shfl_down(o1, off);
  }
  if (j == 0) {
    out[g * 2 + 0] = o0 + b2[0];
    out[g * 2 + 1] = o1 + b2[1];
  }
}

extern "C" void kernel_launch(void* const* d_in, const int* in_sizes, int n_in,
                              void* d_out, int out_size, void* d_ws, size_t ws_size,
                              hipStream_t stream) {
  const float* x     = (const float*)d_in[0];
  const int*   ei    = (const int*)d_in[1];
  const int*   batch = (const int*)d_in[2];
  const float* Wenc  = (const float*)d_in[3];
  const float* benc  = (const float*)d_in[4];
  const float* gamma = (const float*)d_in[5];
  const float* beta  = (const float*)d_in[6];
  const float* mean  = (const float*)d_in[7];
  const float* var   = (const float*)d_in[8];
  const float* Wgcn  = (const float*)d_in[9];
  const float* bgcn  = (const float*)d_in[10];
  const float* W1    = (const float*)d_in[11];
  const float* b1    = (const float*)d_in[12];
  const float* W2    = (const float*)d_in[13];
  const float* b2    = (const float*)d_in[14];
  float* out = (float*)d_out;

  char* ws = (char*)d_ws;
  float*          gsum      = (float*)ws;          ws += (size_t)N_GRAPHS * 64 * 4;
  int*            cnt       = (int*)ws;            ws += (size_t)NBUCK * FBLK * 4;
  int*            tot       = (int*)ws;            ws += 128 * 4;
  int*            basep     = (int*)ws;            ws += 128 * 4;
  int*            binned    = (int*)ws;            ws += (size_t)N_EDGES * 4;
  int*            csr       = (int*)ws;            ws += (size_t)N_EDGES * 4;
  int*            row_start = (int*)ws;            ws += (size_t)(N_NODES + 32) * 4;
  float*          dis       = (float*)ws;          ws += (size_t)N_NODES * 4;
  unsigned short* hws       = (unsigned short*)ws; ws += (size_t)N_NODES * 64 * 2;

  k_cnt<<<FBLK, 256, 0, stream>>>(ei, cnt, gsum);
  k_colscan<<<NBUCK, 256, 0, stream>>>(cnt, tot);
  k_base<<<1, 128, 0, stream>>>(tot, basep);
  k_fill<<<FBLK, 256, 0, stream>>>(ei, cnt, basep, binned);
  k_csr<<<NBUCK, 1024, 0, stream>>>(basep, binned, csr, row_start, dis);
  k_enc<<<(N_NODES / 16 + 3) / 4, 256, 0, stream>>>(x, Wenc, benc, gamma, beta, mean, var,
                                                    Wgcn, dis, hws);
  k_gather<<<(N_NODES / 16), 256, 0, stream>>>(row_start, csr, dis, hws, batch, bgcn, gsum);
  k_cls<<<N_GRAPHS, 64, 0, stream>>>(gsum, batch, W1, b1, W2, b2, out);
}

// Round 10
// 195.196 us; speedup vs baseline: 1.4270x; 1.0272x over previous
//
#include <hip/hip_runtime.h>

#define N_NODES  100000
#define N_EDGES  1200000
#define N_GRAPHS 1024

#define BUCK_SHIFT 10
#define BUCK_NODES 1024
#define NBUCK 98                     // ceil(100000/1024)
#define FBLK  512                    // cnt/fill blocks
#define CHUNK ((N_EDGES + FBLK - 1) / FBLK)   // 2344

// bf16 pack/unpack (RNE)
__device__ __forceinline__ unsigned short f2bf(float f) {
  unsigned u = __float_as_uint(f);
  return (unsigned short)((u + 0x7fffu + ((u >> 16) & 1u)) >> 16);
}
__device__ __forceinline__ float bf2f(unsigned short b) {
  return __uint_as_float(((unsigned)b) << 16);
}

// ---- pass 1: per-block bucket histogram -> cnt[b*FBLK+blk]; also zero gsum ----
__global__ __launch_bounds__(256) void k_cnt(const int* __restrict__ ei,
                                             int* __restrict__ cnt,
                                             float* __restrict__ gsum) {
  __shared__ int h[NBUCK];
  int t = threadIdx.x;
  for (int i = t; i < NBUCK; i += 256) h[i] = 0;
  int gi = blockIdx.x * 256 + t;
  if (gi < N_GRAPHS * 64) gsum[gi] = 0.f;
  __syncthreads();
  int start = blockIdx.x * CHUNK, end = min(start + CHUNK, N_EDGES);
  for (int e = start + t; e < end; e += 256)
    atomicAdd(&h[ei[N_EDGES + e] >> BUCK_SHIFT], 1);
  __syncthreads();
  for (int b = t; b < NBUCK; b += 256)
    cnt[b * FBLK + blockIdx.x] = h[b];
}

// ---- per-bucket exclusive scan over the 512 block counts (in place); totals ----
__global__ __launch_bounds__(256) void k_colscan(int* __restrict__ cnt,
                                                 int* __restrict__ tot) {
  __shared__ int wsum[4];
  int b = blockIdx.x, t = threadIdx.x;
  int v0 = cnt[b * FBLK + 2 * t], v1 = cnt[b * FBLK + 2 * t + 1];
  int a = v0 + v1;
  int lane = t & 63, w = t >> 6;
  int incl = a;
  #pragma unroll
  for (int off = 1; off < 64; off <<= 1) {
    int y = __shfl_up(incl, off);
    if (lane >= off) incl += y;
  }
  if (lane == 63) wsum[w] = incl;
  __syncthreads();
  if (t == 0) {
    int s = 0;
    #pragma unroll
    for (int i = 0; i < 4; ++i) { int x = wsum[i]; wsum[i] = s; s += x; }
    tot[b] = s;
  }
  __syncthreads();
  int excl = wsum[w] + incl - a;
  cnt[b * FBLK + 2 * t] = excl;
  cnt[b * FBLK + 2 * t + 1] = excl + v0;
}

// ---- pass 2: deterministic fill; base scan folded in (LDS, broadcast reads) ----
__global__ __launch_bounds__(256) void k_fill(const int* __restrict__ ei,
                                              const int* __restrict__ cnt,
                                              const int* __restrict__ tot,
                                              int* __restrict__ binned) {
  __shared__ int totS[NBUCK];
  __shared__ int cur[NBUCK];
  int t = threadIdx.x, blk = blockIdx.x;
  if (t < NBUCK) totS[t] = tot[t];
  __syncthreads();
  if (t < NBUCK) {
    int s = 0;
    for (int i = 0; i < t; ++i) s += totS[i];   // same-addr broadcast reads
    cur[t] = s + cnt[t * FBLK + blk];
  }
  __syncthreads();
  int start = blk * CHUNK, end = min(start + CHUNK, N_EDGES);
  for (int e = start + t; e < end; e += 256) {
    int src = ei[e];
    int dst = ei[N_EDGES + e];
    int b = dst >> BUCK_SHIFT;
    int p = atomicAdd(&cur[b], 1);                 // LDS atomic
    binned[p] = src | ((dst & (BUCK_NODES - 1)) << 17);
  }
}

// ---- per-bucket (1024 thr): base reduce + LDS hist+scan -> row_start/dis, sort ----
__global__ __launch_bounds__(1024) void k_csr(const int* __restrict__ tot,
                                              const int* __restrict__ binned,
                                              int* __restrict__ csr,
                                              int* __restrict__ row_start,
                                              float* __restrict__ dis) {
  __shared__ int hist[BUCK_NODES];
  __shared__ int wsum[16];
  __shared__ int b0S;
  int t = threadIdx.x;
  int blk = blockIdx.x;
  int lane = t & 63, w = t >> 6;
  // base[blk] = sum of tot[0..blk-1] via block reduce
  int pv = (t < blk) ? tot[t] : 0;                 // blk <= 97 < 1024
  #pragma unroll
  for (int off = 32; off > 0; off >>= 1) pv += __shfl_down(pv, off);
  if (lane == 0) wsum[w] = pv;
  hist[t] = 0;
  __syncthreads();
  if (t == 0) {
    int s = 0;
    #pragma unroll
    for (int i = 0; i < 16; ++i) s += wsum[i];
    b0S = s;
  }
  __syncthreads();
  int b0 = b0S;
  int nE = tot[blk];
  int node0 = blk << BUCK_SHIFT;
  int nNodes = min(BUCK_NODES, N_NODES - node0);
  for (int i = t; i < nE; i += 1024)
    atomicAdd(&hist[(unsigned)binned[b0 + i] >> 17], 1);
  __syncthreads();
  int v = hist[t];                         // degree of node t in this bucket
  int incl = v;
  #pragma unroll
  for (int off = 1; off < 64; off <<= 1) {
    int y = __shfl_up(incl, off);
    if (lane >= off) incl += y;
  }
  if (lane == 63) wsum[w] = incl;
  __syncthreads();
  if (t == 0) {
    int s = 0;
    #pragma unroll
    for (int i = 0; i < 16; ++i) { int x = wsum[i]; wsum[i] = s; s += x; }
  }
  __syncthreads();
  int excl = wsum[w] + incl - v;
  hist[t] = excl;                          // reuse hist as scatter cursor
  if (t < nNodes) {
    row_start[node0 + t] = b0 + excl;
    dis[node0 + t] = rsqrtf((float)(v + 1));     // +1 self-loop
  }
  if (t == 0 && blk == NBUCK - 1) row_start[N_NODES] = N_EDGES;
  __syncthreads();
  for (int i = t; i < nE; i += 1024) {
    int vv = binned[b0 + i];
    int d = (unsigned)vv >> 17;
    int p = atomicAdd(&hist[d], 1);
    csr[b0 + p] = vv & 0x1FFFF;            // scatter confined to ~49KB region
  }
}

// ---- encoder + BN + h@W_gcn (register W column + readlane broadcast, no LDS),
//      pre-scaled by dis[node], stored bf16 -> hws ----
__global__ __launch_bounds__(256) void k_enc(
    const float* __restrict__ x,
    const float* __restrict__ Wenc, const float* __restrict__ benc,
    const float* __restrict__ gamma, const float* __restrict__ beta,
    const float* __restrict__ mean,  const float* __restrict__ var,
    const float* __restrict__ Wgcn,  const float* __restrict__ dis,
    unsigned short* __restrict__ hws) {
  int lane = threadIdx.x & 63;
  int wv = (blockIdx.x * 256 + threadIdx.x) >> 6;   // 0..6249, 16 nodes each
  float be = benc[lane];
  float sc = gamma[lane] * rsqrtf(var[lane] + 1e-5f);
  float mu = mean[lane], bt = beta[lane];
  float w0 = Wenc[lane], w1 = Wenc[64 + lane], w2 = Wenc[128 + lane], w3 = Wenc[192 + lane];
  float wreg[64];
  #pragma unroll
  for (int k = 0; k < 64; ++k) wreg[k] = Wgcn[k * 64 + lane];   // W column j=lane
  int n0 = wv * 16;
  for (int i = 0; i < 16; ++i) {
    int n = n0 + i;                                  // 6250*16 = 100000 exact
    float4 xv = ((const float4*)x)[n];               // wave-uniform broadcast
    float h = fmaf(xv.w, w3, fmaf(xv.z, w2, fmaf(xv.y, w1, fmaf(xv.x, w0, be))));
    h = fmaxf(h, 0.f);                               // ReLU (dropout = identity)
    float hbn = (h - mu) * sc + bt;                  // BatchNorm (running stats)
    int hb = __float_as_int(hbn);
    float a0 = 0.f, a1 = 0.f, a2 = 0.f, a3 = 0.f;
    #pragma unroll
    for (int k = 0; k < 64; k += 4) {
      a0 = fmaf(__int_as_float(__builtin_amdgcn_readlane(hb, k)),     wreg[k],     a0);
      a1 = fmaf(__int_as_float(__builtin_amdgcn_readlane(hb, k + 1)), wreg[k + 1], a1);
      a2 = fmaf(__int_as_float(__builtin_amdgcn_readlane(hb, k + 2)), wreg[k + 2], a2);
      a3 = fmaf(__int_as_float(__builtin_amdgcn_readlane(hb, k + 3)), wreg[k + 3], a3);
    }
    float acc = ((a0 + a1) + (a2 + a3)) * dis[n];
    hws[(size_t)n * 64 + lane] = f2bf(acc);
  }
}

// ---- CSR gather: 64-thread blocks -> block-uniform node index -> scalar
//      st/en/j -> v_readlane broadcasts + SGPR-base row loads ----
__global__ __launch_bounds__(64) void k_gather(
    const int* __restrict__ row_start, const int* __restrict__ csr,
    const float* __restrict__ dis, const unsigned short* __restrict__ hws,
    const int* __restrict__ batch, const float* __restrict__ bgcn,
    float* __restrict__ gsum) {
  int lane = threadIdx.x;              // one wave per block
  int nb = blockIdx.x * 4;             // 25000 blocks, no tail
  float bias = bgcn[lane];
  float vout[4];
  int gid[4];
  #pragma unroll
  for (int k = 0; k < 4; ++k) {
    int n = nb + k;                    // uniform: blockIdx-derived only
    int st = row_start[n], en = row_start[n + 1];
    float dn = dis[n];
    float a0 = 0.f, a1 = 0.f, a2 = 0.f, a3 = 0.f;
    for (int c = st; c < en; c += 64) {
      int m = min(64, en - c);         // uniform
      int chunk = (c + lane < en) ? csr[c + lane] : 0;   // coalesced load
      int j = 0;
      for (; j + 4 <= m; j += 4) {     // j uniform -> v_readlane w/ SGPR idx
        int s0 = __builtin_amdgcn_readlane(chunk, j);
        int s1 = __builtin_amdgcn_readlane(chunk, j + 1);
        int s2 = __builtin_amdgcn_readlane(chunk, j + 2);
        int s3 = __builtin_amdgcn_readlane(chunk, j + 3);
        a0 += bf2f(hws[(size_t)s0 * 64 + lane]);
        a1 += bf2f(hws[(size_t)s1 * 64 + lane]);
        a2 += bf2f(hws[(size_t)s2 * 64 + lane]);
        a3 += bf2f(hws[(size_t)s3 * 64 + lane]);
      }
      for (; j < m; ++j) {
        int s = __builtin_amdgcn_readlane(chunk, j);
        a0 += bf2f(hws[(size_t)s * 64 + lane]);
      }
    }
    float self = bf2f(hws[(size_t)n * 64 + lane]);
    vout[k] = fmaxf(dn * (((a0 + a1) + (a2 + a3)) + self) + bias, 0.f);
    gid[k] = batch[n];
  }
  float vs = vout[0];
  int cg = gid[0];
  #pragma unroll
  for (int k = 1; k < 4; ++k) {
    if (gid[k] == cg) vs += vout[k];
    else {
      atomicAdd(&gsum[cg * 64 + lane], vs);
      vs = vout[k]; cg = gid[k];
    }
  }
  atomicAdd(&gsum[cg * 64 + lane], vs);
}

// ---- classifier; graph count via binary search on sorted batch ----
__global__ void k_cls(const float* __restrict__ gsum, const int* __restrict__ batch,
                      const float* __restrict__ W1, const float* __restrict__ b1,
                      const float* __restrict__ W2, const float* __restrict__ b2,
                      float* __restrict__ out) {
  __shared__ float gm[64];
  __shared__ int cntS;
  int j = threadIdx.x;
  int g = blockIdx.x;
  if (j == 0) {
    int lo = 0, hi = N_NODES;
    while (lo < hi) { int mid = (lo + hi) >> 1; if (batch[mid] < g) lo = mid + 1; else hi = mid; }
    int lo2 = lo, hi2 = N_NODES;
    while (lo2 < hi2) { int mid = (lo2 + hi2) >> 1; if (batch[mid] < g + 1) lo2 = mid + 1; else hi2 = mid; }
    cntS = lo2 - lo;
  }
  __syncthreads();
  float denom = fmaxf((float)cntS, 1.0f);
  gm[j] = gsum[g * 64 + j] / denom;
  __syncthreads();
  float hid = b1[j];
  #pragma unroll
  for (int k = 0; k < 64; ++k) hid += gm[k] * W1[k * 64 + j];
  hid = fmaxf(hid, 0.f);
  float o0 = hid * W2[j * 2 + 0];
  float o1 = hid * W2[j * 2 + 1];
  #pragma unroll
  for (int off = 32; off > 0; off >>= 1) {
    o0 += __shfl_down(o0, off);
    o1 += __shfl_down(o1, off);
  }
  if (j == 0) {
    out[g * 2 + 0] = o0 + b2[0];
    out[g * 2 + 1] = o1 + b2[1];
  }
}

extern "C" void kernel_launch(void* const* d_in, const int* in_sizes, int n_in,
                              void* d_out, int out_size, void* d_ws, size_t ws_size,
                              hipStream_t stream) {
  const float* x     = (const float*)d_in[0];
  const int*   ei    = (const int*)d_in[1];
  const int*   batch = (const int*)d_in[2];
  const float* Wenc  = (const float*)d_in[3];
  const float* benc  = (const float*)d_in[4];
  const float* gamma = (const float*)d_in[5];
  const float* beta  = (const float*)d_in[6];
  const float* mean  = (const float*)d_in[7];
  const float* var   = (const float*)d_in[8];
  const float* Wgcn  = (const float*)d_in[9];
  const float* bgcn  = (const float*)d_in[10];
  const float* W1    = (const float*)d_in[11];
  const float* b1    = (const float*)d_in[12];
  const float* W2    = (const float*)d_in[13];
  const float* b2    = (const float*)d_in[14];
  float* out = (float*)d_out;

  char* ws = (char*)d_ws;
  float*          gsum      = (float*)ws;          ws += (size_t)N_GRAPHS * 64 * 4;
  int*            cnt       = (int*)ws;            ws += (size_t)NBUCK * FBLK * 4;
  int*            tot       = (int*)ws;            ws += 128 * 4;
  int*            binned    = (int*)ws;            ws += (size_t)N_EDGES * 4;
  int*            csr       = (int*)ws;            ws += (size_t)N_EDGES * 4;
  int*            row_start = (int*)ws;            ws += (size_t)(N_NODES + 32) * 4;
  float*          dis       = (float*)ws;          ws += (size_t)N_NODES * 4;
  unsigned short* hws       = (unsigned short*)ws; ws += (size_t)N_NODES * 64 * 2;

  k_cnt<<<FBLK, 256, 0, stream>>>(ei, cnt, gsum);
  k_colscan<<<NBUCK, 256, 0, stream>>>(cnt, tot);
  k_fill<<<FBLK, 256, 0, stream>>>(ei, cnt, tot, binned);
  k_csr<<<NBUCK, 1024, 0, stream>>>(tot, binned, csr, row_start, dis);
  k_enc<<<(N_NODES / 16 + 3) / 4, 256, 0, stream>>>(x, Wenc, benc, gamma, beta, mean, var,
                                                    Wgcn, dis, hws);
  k_gather<<<(N_NODES / 4), 64, 0, stream>>>(row_start, csr, dis, hws, batch, bgcn, gsum);
  k_cls<<<N_GRAPHS, 64, 0, stream>>>(gsum, batch, W1, b1, W2, b2, out);
}